// Round 7
// baseline (3664.525 us; speedup 1.0000x reference)
//
#include <hip/hip_runtime.h>
#include <hip/hip_cooperative_groups.h>

typedef __attribute__((ext_vector_type(8))) short short8;   // 8 bf16 (4 VGPRs)
typedef __attribute__((ext_vector_type(4))) float f32x4;
typedef __attribute__((ext_vector_type(4))) float floatx4;
typedef __attribute__((ext_vector_type(4))) unsigned int uintx4;
typedef __attribute__((ext_vector_type(2))) unsigned int uintx2;
typedef __attribute__((ext_vector_type(4))) unsigned int u32x4;

#define MFMA16(a, b, c) __builtin_amdgcn_mfma_f32_16x16x32_bf16(a, b, c, 0, 0, 0)

// B=64, S=512, V=32000, D=1024, H=1024, C=1000
#define SB_ROWS 32768   // S*B, row m = s*64 + b

#define AT_LOAD_U32(p)  __hip_atomic_load((p), __ATOMIC_RELAXED, __HIP_MEMORY_SCOPE_AGENT)
#define AT_STORE_U32(p, v) __hip_atomic_store((p), (v), __ATOMIC_RELAXED, __HIP_MEMORY_SCOPE_AGENT)

__device__ __forceinline__ unsigned short f2bf(float f) {
  unsigned u = __float_as_uint(f);
  u += 0x7fffu + ((u >> 16) & 1u);          // RNE
  return (unsigned short)(u >> 16);
}
__device__ __forceinline__ float bf2f(short s) {
  return __uint_as_float(((unsigned)(unsigned short)s) << 16);
}
__device__ __forceinline__ float sigmoidf_(float x) {
  return 1.0f / (1.0f + __expf(-x));
}
__device__ __forceinline__ void gld_lds16(const void* g, void* l) {
  __builtin_amdgcn_global_load_lds(
      (const __attribute__((address_space(1))) unsigned int*)g,
      (__attribute__((address_space(3))) unsigned int*)l, 16, 0, 0);
}

// raw barrier: LDS flush only, NO vmcnt drain (in-flight global loads survive)
#define RAW_BAR()                                            \
  do {                                                       \
    __builtin_amdgcn_sched_barrier(0);                       \
    asm volatile("s_waitcnt lgkmcnt(0)" ::: "memory");       \
    __builtin_amdgcn_s_barrier();                            \
    __builtin_amdgcn_sched_barrier(0);                       \
  } while (0)

// ---------------- f32 -> bf16 cast (n multiple of 4) ----------------
__global__ __launch_bounds__(256) void cast_bf16_k(const float* __restrict__ src,
                                                   short* __restrict__ dst, int n) {
  int i = (blockIdx.x * 256 + threadIdx.x) * 4;
  if (i >= n) return;
  floatx4 v = *(const floatx4*)(src + i);
  unsigned int lo = f2bf(v.x) | ((unsigned)f2bf(v.y) << 16);
  unsigned int hi = f2bf(v.z) | ((unsigned)f2bf(v.w) << 16);
  uintx2 o; o.x = lo; o.y = hi;
  *(uintx2*)(dst + i) = o;
}

// ---------------- embedding gather: xe16[s*64+b][d] = bf16(emb[x[b][s]][d]) ----------------
__global__ __launch_bounds__(128) void embed_gather(const int* __restrict__ x,
                                                    const float* __restrict__ emb,
                                                    short* __restrict__ xe16) {
  const int m = blockIdx.x;            // s*64 + b
  const int s = m >> 6, b = m & 63;
  const int idx = x[b * 512 + s];
  const int d0 = threadIdx.x * 8;
  const float* src = emb + (size_t)idx * 1024 + d0;
  floatx4 a = *(const floatx4*)src;
  floatx4 c = *(const floatx4*)(src + 4);
  uintx4 o;
  o.x = f2bf(a.x) | ((unsigned)f2bf(a.y) << 16);
  o.y = f2bf(a.z) | ((unsigned)f2bf(a.w) << 16);
  o.z = f2bf(c.x) | ((unsigned)f2bf(c.y) << 16);
  o.w = f2bf(c.z) | ((unsigned)f2bf(c.w) << 16);
  *(uintx4*)(xe16 + (size_t)m * 1024 + d0) = o;
}

// ---------------- batched projections: xfi[m][0:1024]=xe@Wf^T+bf, [1024:2048]=xe@Wi^T+bi ----
__global__ __launch_bounds__(256, 2) void gemm_xfi(const short* __restrict__ A,
                                                   const short* __restrict__ Wf,
                                                   const short* __restrict__ Wi,
                                                   const float* __restrict__ bfp,
                                                   const float* __restrict__ bip,
                                                   float* __restrict__ Cout) {
  __shared__ __align__(16) short As[128 * 64];
  __shared__ __align__(16) short Bs[128 * 64];
  const int tid = threadIdx.x;
  const int wave = tid >> 6, lane = tid & 63;
  const int quad = lane >> 4, l15 = lane & 15;
  const int nt = blockIdx.x & 15;
  const long m0 = (long)(blockIdx.x >> 4) * 128;
  const int n0 = nt * 128;
  const short* Bm = (n0 < 1024) ? Wf : Wi;
  const int nb = (n0 < 1024) ? n0 : n0 - 1024;
  const int wm = (wave >> 1) * 64, wn = (wave & 1) * 64;

  f32x4 acc[4][4] = {};
  const int cb = wave * 4;

  for (int k0 = 0; k0 < 1024; k0 += 64) {
    __syncthreads();
#pragma unroll
    for (int q = 0; q < 4; ++q) {
      int Cc = (cb + q) * 64 + lane;
      int row = Cc >> 3, slot = Cc & 7;
      int gk = k0 + ((slot ^ (row & 7)) << 3);
      gld_lds16(A + (m0 + row) * 1024 + gk, As + (size_t)(cb + q) * 512);
      gld_lds16(Bm + (long)(nb + row) * 1024 + gk, Bs + (size_t)(cb + q) * 512);
    }
    __syncthreads();
#pragma unroll
    for (int ks = 0; ks < 2; ++ks) {
      short8 av[4], bv[4];
      const int slin = ks * 4 + quad;
#pragma unroll
      for (int i = 0; i < 4; ++i) {
        int row = wm + i * 16 + l15;
        int slot = slin ^ (row & 7);
        av[i] = *(const short8*)&As[row * 64 + slot * 8];
      }
#pragma unroll
      for (int j = 0; j < 4; ++j) {
        int col = wn + j * 16 + l15;
        int slot = slin ^ (col & 7);
        bv[j] = *(const short8*)&Bs[col * 64 + slot * 8];
      }
#pragma unroll
      for (int i = 0; i < 4; ++i)
#pragma unroll
        for (int j = 0; j < 4; ++j) acc[i][j] = MFMA16(av[i], bv[j], acc[i][j]);
    }
  }
#pragma unroll
  for (int j = 0; j < 4; ++j) {
    int ng = n0 + wn + j * 16 + l15;
    float bias = (ng < 1024) ? bfp[ng] : bip[ng - 1024];
#pragma unroll
    for (int i = 0; i < 4; ++i)
#pragma unroll
      for (int r = 0; r < 4; ++r) {
        long m = m0 + wm + i * 16 + quad * 4 + r;
        Cout[m * 2048 + ng] = acc[i][j][r] + bias;
      }
  }
}

// ---------------- cooperative recurrence: 512 steps, 64 blocks x 512 thr ----------------
// R10 = R9 + protocol polish (cut serialized RTs / drains):
//  - per-(block,coltile) flags: g0 wave ct publishes flg[bid*4+ct]=t+1 right after ITS OWN
//    2-store vmcnt(0) ack. barC deleted.
//  - raw barriers (lgkmcnt only) for barA/barB: in-flight global loads survive.
//  - pf for step t's gate issued at step t HEAD (after poll detect): consumed after barB,
//    slack (stage RT + barA + MFMA) covers HBM latency; poll loop has ZERO outstanding vmem.
//  - granular poll: wave w stages k-cols [w*128,w*128+128) produced by blocks 2w,2w+1 of its
//    rowgroup -> polls their 8 flags only (flg[(ri*16+2w)*4 + 0..7]).
//  - write-after-read safety via 4-deep h ring (write buf[t&3], read buf[(t-1)&3]) + all-16
//    guard (>= t-2) checked before stores; guard flag-load issued at head (latency hidden),
//    re-polled only if stale-fail. 2 steps of straggler slack.
//  - tight spin (no s_sleep); LDS row stride 2064 B (kills 8-way stage-write conflict).
// Safety: overwrite of buf[t&3] at t touches data read at t-3+1=t-2; guard all>=t-2 proves
// every block finished staging at t-2 (flag t-2 stored at end of t-3... flag t-2 published
// end of step t-3 AFTER its stage(t-3)? flag v=k means steps 0..k-1 done; guard >= t-2 means
// all blocks completed step t-3 and are past stage of step t-2... stage(t-2) reads
// buf[(t-3)&3] != buf[t&3]; readers of buf[t&3] content h(t-4)? were at step t-3 (read
// (t-4)&3 = t&3). flag >= t-2 => done step t-3 incl. its stage => safe.
__global__ __launch_bounds__(512, 1) void ran_scan(const float* __restrict__ xfi,
                                                   const short* __restrict__ xe16,
                                                   const short* __restrict__ Uf,
                                                   const short* __restrict__ Ui,
                                                   short* __restrict__ h16,
                                                   unsigned* __restrict__ flg) {
  __shared__ __align__(16) char hs_b[16 * 2064];     // staged A-rows, padded stride
  __shared__ float exch[4][4][64];                   // i-gate partials
  const int tid = threadIdx.x;
  const int wave = tid >> 6, lane = tid & 63;
  const int ct = wave >> 1, g = wave & 1;            // coltile, gate
  const int quad = lane >> 4, l15 = lane & 15;
  const int ri = blockIdx.x >> 4, cj = blockIdx.x & 15;
  const int rowbase = ri * 16;                       // batch rows
  const int colbase = cj * 64 + ct * 16;             // h cols of this wave

  // U fragments -> registers (B-operand layout: col=l15, k=s*32+quad*8)
  short8 bU[32];
  {
    const short* U = g ? Ui : Uf;
#pragma unroll
    for (int s = 0; s < 32; ++s)
      bU[s] = *(const short8*)&U[(size_t)(colbase + l15) * 1024 + s * 32 + quad * 8];
  }

  float hreg[4] = {};                 // fp32 h master (f-waves), rows rowbase+quad*4+r
  float xfc[4], xic[4], xec[4];       // current-step inputs
  if (g == 0) {
#pragma unroll
    for (int r = 0; r < 4; ++r) {
      int m = rowbase + quad * 4 + r;                // t=0 rows
      xfc[r] = xfi[(size_t)m * 2048 + colbase + l15];
      xic[r] = xfi[(size_t)m * 2048 + 1024 + colbase + l15];
      xec[r] = bf2f(xe16[(size_t)m * 1024 + colbase + l15]);
    }
  }

  const char* hbase = (const char*)h16;
  // stage: wave w loads k-chunks w*16..+16 for rows rowbase..+16 (4 KB, disjoint)
  const size_t stage_off =
      (size_t)(rowbase + quad) * 2048 + (size_t)wave * 256 + (size_t)l15 * 16;
  const unsigned* pollp = flg + ((size_t)(ri * 16 + 2 * wave) * 4 + (lane & 7));
  const unsigned* guardp = flg + ((size_t)ri * 64 + lane);

#define GLDP(dst, p)                                                         \
  asm volatile("global_load_dwordx4 %0, %1, off sc0 sc1"                     \
               : "=&v"(dst) : "v"(p) : "memory")
#define GLDW(dst, p)                                                         \
  asm volatile("global_load_dword %0, %1, off sc0 sc1"                       \
               : "=&v"(dst) : "v"(p) : "memory")

  for (int t = 0; t < 512; ++t) {
    f32x4 a0 = {0.f, 0.f, 0.f, 0.f}, a1 = a0;
    unsigned gv = 0xffffffffu;                       // guard value (early-loaded)
    if (t > 0) {
      // ---- granular poll: my 2 producer blocks (8 flags), tight spin, clean vmem ----
      {
        unsigned v = AT_LOAD_U32(pollp);
        while (!__all((int)(v >= (unsigned)t))) v = AT_LOAD_U32(pollp);
        asm volatile("" ::: "memory");
        __builtin_amdgcn_sched_barrier(0);
      }
      // ---- early guard load (consumed before stores; latency hidden) ----
      GLDW(gv, guardp);
      // ---- stage my 4 KB slice: 4 coherent dwordx4, one RT ----
      const char* ab = hbase + (size_t)((t - 1) & 3) * 131072 + stage_off;
      u32x4 S0, S1, S2, S3;
      GLDP(S0, ab);
      GLDP(S1, ab + 8192);
      GLDP(S2, ab + 16384);
      GLDP(S3, ab + 24576);
      __builtin_amdgcn_sched_barrier(0);
      // ---- pf this step's gate inputs (g0): 12 HBM loads, consumed after barB ----
      if (g == 0) {
        const size_t mb = (size_t)t * 64;
#pragma unroll
        for (int r = 0; r < 4; ++r) {
          size_t m = mb + rowbase + quad * 4 + r;
          xfc[r] = xfi[m * 2048 + colbase + l15];
          xic[r] = xfi[m * 2048 + 1024 + colbase + l15];
          xec[r] = bf2f(xe16[m * 1024 + colbase + l15]);
        }
        __builtin_amdgcn_sched_barrier(0);
        asm volatile("s_waitcnt vmcnt(12)" ::: "memory");   // guard+stage done, pf in flight
      } else {
        __builtin_amdgcn_sched_barrier(0);
        asm volatile("s_waitcnt vmcnt(0)" ::: "memory");    // guard+stage done
      }
      __builtin_amdgcn_sched_barrier(0);
      // swizzled LDS writes: chunk kc = wave*16 + l15, row = j*4 + quad
#pragma unroll
      for (int j = 0; j < 4; ++j) {
        const int row = j * 4 + quad;
        const int kc = wave * 16 + l15;
        u32x4 S = (j == 0) ? S0 : (j == 1) ? S1 : (j == 2) ? S2 : S3;
        *(short8*)&hs_b[row * 2064 + ((kc ^ (row & 7)) << 4)] =
            __builtin_bit_cast(short8, S);
      }
    }
    RAW_BAR();   // barrier A: h_s staged (t=0: h=0, skip compute)
    if (t > 0) {
#pragma unroll
      for (int s = 0; s < 32; ++s) {
        short8 a = *(const short8*)
            &hs_b[l15 * 2064 + (((s * 4 + quad) ^ (l15 & 7)) << 4)];
        if (s & 1) a1 = MFMA16(a, bU[s], a1);
        else       a0 = MFMA16(a, bU[s], a0);
      }
    }
    if (g == 1) {
#pragma unroll
      for (int r = 0; r < 4; ++r) exch[ct][r][lane] = a0[r] + a1[r];
    }
    RAW_BAR();   // barrier B: i-gate partials visible
    if (g == 0) {
      unsigned short hb[4];
#pragma unroll
      for (int r = 0; r < 4; ++r) {
        float sf = a0[r] + a1[r];
        float si = exch[ct][r][lane];
        float fg = sigmoidf_(xfc[r] + sf);
        float ig = sigmoidf_(xic[r] + si);
        float hn = fg * hreg[r] + ig * xec[r];
        hreg[r] = hn;
        hb[r] = f2bf(hn);
      }
      // ---- all-16 guard (>= t-2) before overwriting ring slot t&3 ----
      if (t >= 2) {
        asm volatile("s_waitcnt vmcnt(0)" ::: "memory");   // gv (and stores-none) ready
        unsigned thr = (unsigned)(t - 2);
        while (!__all((int)(gv >= thr))) gv = AT_LOAD_U32(guardp);
        asm volatile("" ::: "memory");
      }
      // paired coherent stores into ring slot t&3
      {
        unsigned* hwp = (unsigned*)(h16 + (size_t)(t & 3) * 65536);
        unsigned p01 = hb[0] | ((unsigned)hb[1] << 16);
        unsigned p23 = hb[2] | ((unsigned)hb[3] << 16);
        unsigned q01 = (unsigned)__shfl_xor((int)p01, 1, 64);
        unsigned q23 = (unsigned)__shfl_xor((int)p23, 1, 64);
        const int cph = (colbase + (l15 & ~1)) >> 1;   // dword col index
        const int rbase = rowbase + quad * 4;
        if (!(l15 & 1)) {
          unsigned dw0 = (p01 & 0xffffu) | (q01 << 16);
          unsigned dw1 = (p01 >> 16) | (q01 & 0xffff0000u);
          AT_STORE_U32(hwp + (size_t)(rbase + 0) * 512 + cph, dw0);
          AT_STORE_U32(hwp + (size_t)(rbase + 1) * 512 + cph, dw1);
        } else {
          unsigned dw2 = (q23 & 0xffffu) | (p23 << 16);
          unsigned dw3 = (q23 >> 16) | (p23 & 0xffff0000u);
          AT_STORE_U32(hwp + (size_t)(rbase + 2) * 512 + cph, dw2);
          AT_STORE_U32(hwp + (size_t)(rbase + 3) * 512 + cph, dw3);
        }
      }
      if (t < 511) {
        // own-store ack, then per-wave flag publish (no barC, no full drain)
        asm volatile("s_waitcnt vmcnt(0)" ::: "memory");
        if (lane == 0)
          AT_STORE_U32(flg + ((size_t)blockIdx.x * 4 + ct), (unsigned)(t + 1));
      }
    }
  }
#undef GLDP
#undef GLDW
  // t=511 wrote ring slot 3. fc_kernel launch's implicit acquire makes it visible.
}

// ---------------- final FC: out[b][c] = h @ fc_w^T + fc_b (c < 1000) ----------------
__global__ __launch_bounds__(256) void fc_kernel(const short* __restrict__ h16,
                                                 const short* __restrict__ fcw16,
                                                 const float* __restrict__ fcb,
                                                 float* __restrict__ out) {
  const int tid = threadIdx.x;
  const int wave = tid >> 6, lane = tid & 63;
  const int quad = lane >> 4, l15 = lane & 15;
  const int c = blockIdx.x * 64 + wave * 16 + l15;
  f32x4 acc[4] = {};
#pragma unroll
  for (int kc = 0; kc < 32; ++kc) {
    int k = kc * 32 + quad * 8;
    short8 b = *(const short8*)&fcw16[(size_t)c * 1024 + k];
#pragma unroll
    for (int i = 0; i < 4; ++i) {
      short8 a = *(const short8*)&h16[(size_t)(i * 16 + l15) * 1024 + k];
      acc[i] = MFMA16(a, b, acc[i]);
    }
  }
  if (c < 1000) {
    float bias = fcb[c];
#pragma unroll
    for (int i = 0; i < 4; ++i)
#pragma unroll
      for (int r = 0; r < 4; ++r) {
        int m = i * 16 + quad * 4 + r;
        out[m * 1000 + c] = acc[i][r] + bias;
      }
  }
}

extern "C" void kernel_launch(void* const* d_in, const int* in_sizes, int n_in,
                              void* d_out, int out_size, void* d_ws, size_t ws_size,
                              hipStream_t stream) {
  const int* x = (const int*)d_in[0];
  const float* emb = (const float*)d_in[1];
  const float* Wf_w = (const float*)d_in[2];
  const float* Wf_b = (const float*)d_in[3];
  const float* Uf_w = (const float*)d_in[4];
  const float* Wi_w = (const float*)d_in[5];
  const float* Wi_b = (const float*)d_in[6];
  const float* Ui_w = (const float*)d_in[7];
  const float* fc_w = (const float*)d_in[8];
  const float* fc_b = (const float*)d_in[9];
  float* out = (float*)d_out;

  char* ws = (char*)d_ws;
  size_t off = 0;
  auto alloc = [&](size_t bytes) {
    char* p = ws + off;
    off += (bytes + 255) & ~(size_t)255;
    return p;
  };
  short* xe16 = (short*)alloc((size_t)SB_ROWS * 1024 * 2);       // 64 MB
  float* xfi  = (float*)alloc((size_t)SB_ROWS * 2048 * 4);       // 256 MB
  short* Wf16 = (short*)alloc(1024ull * 1024 * 2);
  short* Wi16 = (short*)alloc(1024ull * 1024 * 2);
  short* Uf16 = (short*)alloc(1024ull * 1024 * 2);
  short* Ui16 = (short*)alloc(1024ull * 1024 * 2);
  short* fcw16 = (short*)alloc(1024ull * 1024 * 2);
  short* h16 = (short*)alloc(4ull * 65536 * 2);                  // 4-deep bf16 h ring
  unsigned* flg = (unsigned*)alloc(256 * sizeof(unsigned));      // per-(block,ct) step flags
  if (off > ws_size) return;

  hipMemsetAsync((void*)flg, 0, 256 * sizeof(unsigned), stream);
  cast_bf16_k<<<1024, 256, 0, stream>>>(Wf_w, Wf16, 1024 * 1024);
  cast_bf16_k<<<1024, 256, 0, stream>>>(Wi_w, Wi16, 1024 * 1024);
  cast_bf16_k<<<1024, 256, 0, stream>>>(Uf_w, Uf16, 1024 * 1024);
  cast_bf16_k<<<1024, 256, 0, stream>>>(Ui_w, Ui16, 1024 * 1024);
  cast_bf16_k<<<1000, 256, 0, stream>>>(fc_w, fcw16, 1000 * 1024);
  embed_gather<<<SB_ROWS, 128, 0, stream>>>(x, emb, xe16);
  gemm_xfi<<<(SB_ROWS / 128) * 16, 256, 0, stream>>>(xe16, Wf16, Wi16, Wf_b, Wi_b, xfi);

  const float* xfi_a = xfi;
  const short* xe_a = xe16;
  const short* uf_a = Uf16;
  const short* ui_a = Ui16;
  short* h16_a = h16;
  unsigned* flg_a = flg;
  void* args[] = {(void*)&xfi_a, (void*)&xe_a, (void*)&uf_a,
                  (void*)&ui_a,  (void*)&h16_a, (void*)&flg_a};
  (void)hipLaunchCooperativeKernel((void*)ran_scan, dim3(64), dim3(512), args, 0, stream);

  // after t=511: final h is in ring slot 3
  fc_kernel<<<16, 256, 0, stream>>>(h16 + 3 * 65536, fcw16, fc_b, out);
}

// Round 8
// 3025.018 us; speedup vs baseline: 1.2114x; 1.2114x over previous
//
#include <hip/hip_runtime.h>
#include <hip/hip_cooperative_groups.h>

typedef __attribute__((ext_vector_type(8))) short short8;   // 8 bf16 (4 VGPRs)
typedef __attribute__((ext_vector_type(4))) float f32x4;
typedef __attribute__((ext_vector_type(4))) float floatx4;
typedef __attribute__((ext_vector_type(4))) unsigned int uintx4;
typedef __attribute__((ext_vector_type(2))) unsigned int uintx2;
typedef __attribute__((ext_vector_type(4))) unsigned int u32x4;

#define MFMA16(a, b, c) __builtin_amdgcn_mfma_f32_16x16x32_bf16(a, b, c, 0, 0, 0)

// B=64, S=512, V=32000, D=1024, H=1024, C=1000
#define SB_ROWS 32768   // S*B, row m = s*64 + b

#define AT_LOAD_U32(p)  __hip_atomic_load((p), __ATOMIC_RELAXED, __HIP_MEMORY_SCOPE_AGENT)
#define AT_STORE_U32(p, v) __hip_atomic_store((p), (v), __ATOMIC_RELAXED, __HIP_MEMORY_SCOPE_AGENT)

__device__ __forceinline__ unsigned short f2bf(float f) {
  unsigned u = __float_as_uint(f);
  u += 0x7fffu + ((u >> 16) & 1u);          // RNE
  return (unsigned short)(u >> 16);
}
__device__ __forceinline__ float bf2f(short s) {
  return __uint_as_float(((unsigned)(unsigned short)s) << 16);
}
__device__ __forceinline__ float sigmoidf_(float x) {
  return 1.0f / (1.0f + __expf(-x));
}
__device__ __forceinline__ void gld_lds16(const void* g, void* l) {
  __builtin_amdgcn_global_load_lds(
      (const __attribute__((address_space(1))) unsigned int*)g,
      (__attribute__((address_space(3))) unsigned int*)l, 16, 0, 0);
}

// raw barrier: LDS flush only, NO vmcnt drain (in-flight global loads survive)
#define RAW_BAR()                                            \
  do {                                                       \
    __builtin_amdgcn_sched_barrier(0);                       \
    asm volatile("s_waitcnt lgkmcnt(0)" ::: "memory");       \
    __builtin_amdgcn_s_barrier();                            \
    __builtin_amdgcn_sched_barrier(0);                       \
  } while (0)

// ---------------- f32 -> bf16 cast (n multiple of 4) ----------------
__global__ __launch_bounds__(256) void cast_bf16_k(const float* __restrict__ src,
                                                   short* __restrict__ dst, int n) {
  int i = (blockIdx.x * 256 + threadIdx.x) * 4;
  if (i >= n) return;
  floatx4 v = *(const floatx4*)(src + i);
  unsigned int lo = f2bf(v.x) | ((unsigned)f2bf(v.y) << 16);
  unsigned int hi = f2bf(v.z) | ((unsigned)f2bf(v.w) << 16);
  uintx2 o; o.x = lo; o.y = hi;
  *(uintx2*)(dst + i) = o;
}

// ---------------- embedding gather: xe16[s*64+b][d] = bf16(emb[x[b][s]][d]) ----------------
__global__ __launch_bounds__(128) void embed_gather(const int* __restrict__ x,
                                                    const float* __restrict__ emb,
                                                    short* __restrict__ xe16) {
  const int m = blockIdx.x;            // s*64 + b
  const int s = m >> 6, b = m & 63;
  const int idx = x[b * 512 + s];
  const int d0 = threadIdx.x * 8;
  const float* src = emb + (size_t)idx * 1024 + d0;
  floatx4 a = *(const floatx4*)src;
  floatx4 c = *(const floatx4*)(src + 4);
  uintx4 o;
  o.x = f2bf(a.x) | ((unsigned)f2bf(a.y) << 16);
  o.y = f2bf(a.z) | ((unsigned)f2bf(a.w) << 16);
  o.z = f2bf(c.x) | ((unsigned)f2bf(c.y) << 16);
  o.w = f2bf(c.z) | ((unsigned)f2bf(c.w) << 16);
  *(uintx4*)(xe16 + (size_t)m * 1024 + d0) = o;
}

// ---------------- batched projections: xfi[m][0:1024]=xe@Wf^T+bf, [1024:2048]=xe@Wi^T+bi ----
__global__ __launch_bounds__(256, 2) void gemm_xfi(const short* __restrict__ A,
                                                   const short* __restrict__ Wf,
                                                   const short* __restrict__ Wi,
                                                   const float* __restrict__ bfp,
                                                   const float* __restrict__ bip,
                                                   float* __restrict__ Cout) {
  __shared__ __align__(16) short As[128 * 64];
  __shared__ __align__(16) short Bs[128 * 64];
  const int tid = threadIdx.x;
  const int wave = tid >> 6, lane = tid & 63;
  const int quad = lane >> 4, l15 = lane & 15;
  const int nt = blockIdx.x & 15;
  const long m0 = (long)(blockIdx.x >> 4) * 128;
  const int n0 = nt * 128;
  const short* Bm = (n0 < 1024) ? Wf : Wi;
  const int nb = (n0 < 1024) ? n0 : n0 - 1024;
  const int wm = (wave >> 1) * 64, wn = (wave & 1) * 64;

  f32x4 acc[4][4] = {};
  const int cb = wave * 4;

  for (int k0 = 0; k0 < 1024; k0 += 64) {
    __syncthreads();
#pragma unroll
    for (int q = 0; q < 4; ++q) {
      int Cc = (cb + q) * 64 + lane;
      int row = Cc >> 3, slot = Cc & 7;
      int gk = k0 + ((slot ^ (row & 7)) << 3);
      gld_lds16(A + (m0 + row) * 1024 + gk, As + (size_t)(cb + q) * 512);
      gld_lds16(Bm + (long)(nb + row) * 1024 + gk, Bs + (size_t)(cb + q) * 512);
    }
    __syncthreads();
#pragma unroll
    for (int ks = 0; ks < 2; ++ks) {
      short8 av[4], bv[4];
      const int slin = ks * 4 + quad;
#pragma unroll
      for (int i = 0; i < 4; ++i) {
        int row = wm + i * 16 + l15;
        int slot = slin ^ (row & 7);
        av[i] = *(const short8*)&As[row * 64 + slot * 8];
      }
#pragma unroll
      for (int j = 0; j < 4; ++j) {
        int col = wn + j * 16 + l15;
        int slot = slin ^ (col & 7);
        bv[j] = *(const short8*)&Bs[col * 64 + slot * 8];
      }
#pragma unroll
      for (int i = 0; i < 4; ++i)
#pragma unroll
        for (int j = 0; j < 4; ++j) acc[i][j] = MFMA16(av[i], bv[j], acc[i][j]);
    }
  }
#pragma unroll
  for (int j = 0; j < 4; ++j) {
    int ng = n0 + wn + j * 16 + l15;
    float bias = (ng < 1024) ? bfp[ng] : bip[ng - 1024];
#pragma unroll
    for (int i = 0; i < 4; ++i)
#pragma unroll
      for (int r = 0; r < 4; ++r) {
        long m = m0 + wm + i * 16 + quad * 4 + r;
        Cout[m * 2048 + ng] = acc[i][j][r] + bias;
      }
  }
}

// ---------------- cooperative recurrence: 512 steps, 64 blocks x 512 thr ----------------
// R11 = R9 (proven 2330us) + three targeted changes:
//  (1) wave0-only poll: 64 lanes <-> 64 per-(block,ct) flags of the rowgroup, s_sleep(1)
//      backoff, release via raw barrier (barP). 8x less coherent poll traffic -> the flag
//      lines' LLC slices stop saturating (R9: 512thr x 64blk on 1-2 lines).
//  (2) per-(block,ct) flags published by each g0 wave right after ITS OWN 2-store ack —
//      barC and the tid0-publish rendezvous are gone. Safety: flag(bid,ct) >= t implies
//      block bid passed barA(t-1), i.e. finished ALL its stage-reads of the buffer that
//      step t overwrites (stage reads happen before barA; stores/flags after barB).
//  (3) pf for step t's gate inputs issued at step HEAD right after the 4 stage loads:
//      vmcnt(12) waits stage only; pf drains under MFMA+barriers, consumed after barB.
//      The store-ack window at the tail contains ONLY the 2 stores.
// LDS: stride 2048 + XOR swizzle (R9 exact — conflict-free; R10's 2064 pad broke it).
// Ping-pong: step t reads buf[t&1] (h(t-1)), writes buf[(t&1)^1].
__global__ __launch_bounds__(512, 1) void ran_scan(const float* __restrict__ xfi,
                                                   const short* __restrict__ xe16,
                                                   const short* __restrict__ Uf,
                                                   const short* __restrict__ Ui,
                                                   short* __restrict__ h16,
                                                   unsigned* __restrict__ flg) {
  __shared__ __align__(16) short h_s[16 * 1024];     // 32 KB staged A-rows (swizzled)
  __shared__ float exch[4][4][64];                   // i-gate partials
  const int tid = threadIdx.x;
  const int wave = tid >> 6, lane = tid & 63;
  const int ct = wave >> 1, g = wave & 1;            // coltile, gate
  const int quad = lane >> 4, l15 = lane & 15;
  const int ri = blockIdx.x >> 4, cj = blockIdx.x & 15;
  const int rowbase = ri * 16;                       // batch rows
  const int colbase = cj * 64 + ct * 16;             // h cols of this wave

  // U fragments -> registers (B-operand layout: col=l15, k=s*32+quad*8)
  short8 bU[32];
  {
    const short* U = g ? Ui : Uf;
#pragma unroll
    for (int s = 0; s < 32; ++s)
      bU[s] = *(const short8*)&U[(size_t)(colbase + l15) * 1024 + s * 32 + quad * 8];
  }

  float hreg[4] = {};                 // fp32 h master (g0 waves), rows rowbase+quad*4+r
  float xfc[4], xic[4], xec[4];       // current-step inputs
  if (g == 0) {
#pragma unroll
    for (int r = 0; r < 4; ++r) {
      int m = rowbase + quad * 4 + r;                // t=0 rows
      xfc[r] = xfi[(size_t)m * 2048 + colbase + l15];
      xic[r] = xfi[(size_t)m * 2048 + 1024 + colbase + l15];
      xec[r] = bf2f(xe16[(size_t)m * 1024 + colbase + l15]);
    }
  }

  char* hs_b = (char*)h_s;
  const char* hbase = (const char*)h16;
  // stage: wave w loads k-chunks w*16..+16 for rows rowbase..+16 (4 KB, disjoint)
  const size_t stage_off =
      (size_t)(rowbase + quad) * 2048 + (size_t)wave * 256 + (size_t)l15 * 16;
  const unsigned* pollp = flg + ((size_t)ri * 64 + lane);   // wave0: 64 flags of rowgroup

#define GLDP(dst, p)                                                         \
  asm volatile("global_load_dwordx4 %0, %1, off sc0 sc1"                     \
               : "=&v"(dst) : "v"(p) : "memory")

  for (int t = 0; t < 512; ++t) {
    const int rp = t & 1;
    f32x4 a0 = {0.f, 0.f, 0.f, 0.f}, a1 = a0;
    if (t > 0) {
      // ---- wave0-only poll of the rowgroup's 64 per-(block,ct) flags ----
      if (wave == 0) {
        unsigned v = AT_LOAD_U32(pollp);
        while (!__all((int)(v >= (unsigned)t))) {
          __builtin_amdgcn_s_sleep(1);
          v = AT_LOAD_U32(pollp);
        }
        asm volatile("" ::: "memory");
      }
      RAW_BAR();   // barP: release block after poll
      // ---- stage my 4 KB slice: 4 coherent dwordx4, one RT ----
      const char* ab = hbase + (size_t)rp * 131072 + stage_off;
      u32x4 S0, S1, S2, S3;
      GLDP(S0, ab);
      GLDP(S1, ab + 8192);
      GLDP(S2, ab + 16384);
      GLDP(S3, ab + 24576);
      __builtin_amdgcn_sched_barrier(0);
      // ---- pf this step's gate inputs (g0): 12 loads AFTER stage (younger in vmcnt) ----
      if (g == 0) {
        const size_t mb = (size_t)t * 64;
#pragma unroll
        for (int r = 0; r < 4; ++r) {
          size_t m = mb + rowbase + quad * 4 + r;
          xfc[r] = xfi[m * 2048 + colbase + l15];
          xic[r] = xfi[m * 2048 + 1024 + colbase + l15];
          xec[r] = bf2f(xe16[m * 1024 + colbase + l15]);
        }
        __builtin_amdgcn_sched_barrier(0);
        asm volatile("s_waitcnt vmcnt(12)" ::: "memory");   // stage done, pf in flight
      } else {
        __builtin_amdgcn_sched_barrier(0);
        asm volatile("s_waitcnt vmcnt(0)" ::: "memory");    // stage done
      }
      __builtin_amdgcn_sched_barrier(0);
      // swizzled LDS writes: chunk kc = wave*16 + l15, row = j*4 + quad (stride 2048!)
#pragma unroll
      for (int j = 0; j < 4; ++j) {
        const int row = j * 4 + quad;
        const int kc = wave * 16 + l15;
        u32x4 S = (j == 0) ? S0 : (j == 1) ? S1 : (j == 2) ? S2 : S3;
        *(short8*)&hs_b[row * 2048 + ((kc ^ (row & 7)) << 4)] =
            __builtin_bit_cast(short8, S);
      }
    }
    RAW_BAR();   // barrier A: h_s staged (t=0: h=0, skip compute)
    if (t > 0) {
#pragma unroll
      for (int s = 0; s < 32; ++s) {
        short8 a = *(const short8*)
            &hs_b[l15 * 2048 + (((s * 4 + quad) ^ (l15 & 7)) << 4)];
        if (s & 1) a1 = MFMA16(a, bU[s], a1);
        else       a0 = MFMA16(a, bU[s], a0);
      }
    }
    if (g == 1) {
#pragma unroll
      for (int r = 0; r < 4; ++r) exch[ct][r][lane] = a0[r] + a1[r];
    }
    RAW_BAR();   // barrier B: i-gate partials visible
    if (g == 0) {
      // pf (12 loads) must have landed; MFMA+barriers covered most of the latency
      asm volatile("s_waitcnt vmcnt(0)" ::: "memory");
      unsigned short hb[4];
#pragma unroll
      for (int r = 0; r < 4; ++r) {
        float sf = a0[r] + a1[r];
        float si = exch[ct][r][lane];
        float fg = sigmoidf_(xfc[r] + sf);
        float ig = sigmoidf_(xic[r] + si);
        float hn = fg * hreg[r] + ig * xec[r];
        hreg[r] = hn;
        hb[r] = f2bf(hn);
      }
      // paired coherent stores into buf[(t&1)^1]
      {
        unsigned* hwp = (unsigned*)(h16 + (size_t)(rp ^ 1) * 65536);
        unsigned p01 = hb[0] | ((unsigned)hb[1] << 16);
        unsigned p23 = hb[2] | ((unsigned)hb[3] << 16);
        unsigned q01 = (unsigned)__shfl_xor((int)p01, 1, 64);
        unsigned q23 = (unsigned)__shfl_xor((int)p23, 1, 64);
        const int cph = (colbase + (l15 & ~1)) >> 1;   // dword col index
        const int rbase = rowbase + quad * 4;
        if (!(l15 & 1)) {
          unsigned dw0 = (p01 & 0xffffu) | (q01 << 16);
          unsigned dw1 = (p01 >> 16) | (q01 & 0xffff0000u);
          AT_STORE_U32(hwp + (size_t)(rbase + 0) * 512 + cph, dw0);
          AT_STORE_U32(hwp + (size_t)(rbase + 1) * 512 + cph, dw1);
        } else {
          unsigned dw2 = (q23 & 0xffffu) | (p23 << 16);
          unsigned dw3 = (q23 >> 16) | (p23 & 0xffff0000u);
          AT_STORE_U32(hwp + (size_t)(rbase + 2) * 512 + cph, dw2);
          AT_STORE_U32(hwp + (size_t)(rbase + 3) * 512 + cph, dw3);
        }
      }
      if (t < 511) {
        // own-store ack (only the 2 stores are outstanding), then per-ct flag publish
        __builtin_amdgcn_sched_barrier(0);
        asm volatile("s_waitcnt vmcnt(0)" ::: "memory");
        if (lane == 0)
          AT_STORE_U32(flg + ((size_t)blockIdx.x * 4 + ct), (unsigned)(t + 1));
      }
    }
  }
#undef GLDP
  // t=511 wrote buffer 0. fc_kernel launch's implicit acquire makes it visible.
}

// ---------------- final FC: out[b][c] = h @ fc_w^T + fc_b (c < 1000) ----------------
__global__ __launch_bounds__(256) void fc_kernel(const short* __restrict__ h16,
                                                 const short* __restrict__ fcw16,
                                                 const float* __restrict__ fcb,
                                                 float* __restrict__ out) {
  const int tid = threadIdx.x;
  const int wave = tid >> 6, lane = tid & 63;
  const int quad = lane >> 4, l15 = lane & 15;
  const int c = blockIdx.x * 64 + wave * 16 + l15;
  f32x4 acc[4] = {};
#pragma unroll
  for (int kc = 0; kc < 32; ++kc) {
    int k = kc * 32 + quad * 8;
    short8 b = *(const short8*)&fcw16[(size_t)c * 1024 + k];
#pragma unroll
    for (int i = 0; i < 4; ++i) {
      short8 a = *(const short8*)&h16[(size_t)(i * 16 + l15) * 1024 + k];
      acc[i] = MFMA16(a, b, acc[i]);
    }
  }
  if (c < 1000) {
    float bias = fcb[c];
#pragma unroll
    for (int i = 0; i < 4; ++i)
#pragma unroll
      for (int r = 0; r < 4; ++r) {
        int m = i * 16 + quad * 4 + r;
        out[m * 1000 + c] = acc[i][r] + bias;
      }
  }
}

extern "C" void kernel_launch(void* const* d_in, const int* in_sizes, int n_in,
                              void* d_out, int out_size, void* d_ws, size_t ws_size,
                              hipStream_t stream) {
  const int* x = (const int*)d_in[0];
  const float* emb = (const float*)d_in[1];
  const float* Wf_w = (const float*)d_in[2];
  const float* Wf_b = (const float*)d_in[3];
  const float* Uf_w = (const float*)d_in[4];
  const float* Wi_w = (const float*)d_in[5];
  const float* Wi_b = (const float*)d_in[6];
  const float* Ui_w = (const float*)d_in[7];
  const float* fc_w = (const float*)d_in[8];
  const float* fc_b = (const float*)d_in[9];
  float* out = (float*)d_out;

  char* ws = (char*)d_ws;
  size_t off = 0;
  auto alloc = [&](size_t bytes) {
    char* p = ws + off;
    off += (bytes + 255) & ~(size_t)255;
    return p;
  };
  short* xe16 = (short*)alloc((size_t)SB_ROWS * 1024 * 2);       // 64 MB
  float* xfi  = (float*)alloc((size_t)SB_ROWS * 2048 * 4);       // 256 MB
  short* Wf16 = (short*)alloc(1024ull * 1024 * 2);
  short* Wi16 = (short*)alloc(1024ull * 1024 * 2);
  short* Uf16 = (short*)alloc(1024ull * 1024 * 2);
  short* Ui16 = (short*)alloc(1024ull * 1024 * 2);
  short* fcw16 = (short*)alloc(1024ull * 1024 * 2);
  short* h16 = (short*)alloc(2ull * 65536 * 2);                  // ping-pong bf16 h
  unsigned* flg = (unsigned*)alloc(256 * sizeof(unsigned));      // per-(block,ct) step flags
  if (off > ws_size) return;

  hipMemsetAsync((void*)flg, 0, 256 * sizeof(unsigned), stream);
  cast_bf16_k<<<1024, 256, 0, stream>>>(Wf_w, Wf16, 1024 * 1024);
  cast_bf16_k<<<1024, 256, 0, stream>>>(Wi_w, Wi16, 1024 * 1024);
  cast_bf16_k<<<1024, 256, 0, stream>>>(Uf_w, Uf16, 1024 * 1024);
  cast_bf16_k<<<1024, 256, 0, stream>>>(Ui_w, Ui16, 1024 * 1024);
  cast_bf16_k<<<1000, 256, 0, stream>>>(fc_w, fcw16, 1000 * 1024);
  embed_gather<<<SB_ROWS, 128, 0, stream>>>(x, emb, xe16);
  gemm_xfi<<<(SB_ROWS / 128) * 16, 256, 0, stream>>>(xe16, Wf16, Wi16, Wf_b, Wi_b, xfi);

  const float* xfi_a = xfi;
  const short* xe_a = xe16;
  const short* uf_a = Uf16;
  const short* ui_a = Ui16;
  short* h16_a = h16;
  unsigned* flg_a = flg;
  void* args[] = {(void*)&xfi_a, (void*)&xe_a, (void*)&uf_a,
                  (void*)&ui_a,  (void*)&h16_a, (void*)&flg_a};
  (void)hipLaunchCooperativeKernel((void*)ran_scan, dim3(64), dim3(512), args, 0, stream);

  // after t=511: final h is in buffer 0
  fc_kernel<<<16, 256, 0, stream>>>(h16, fcw16, fc_b, out);
}